// Round 9
// baseline (126.616 us; speedup 1.0000x reference)
//
#include <hip/hip_runtime.h>

typedef __attribute__((ext_vector_type(8))) short short8;
typedef __attribute__((ext_vector_type(4))) float float4v;

#define BATCH 16
#define CDIM 2048
#define LDIM 64
#define BSTRIDE (CDIM * LDIM) /* 131072 elems per batch */

#if __has_builtin(__builtin_amdgcn_exp2f)
#define EXPW(x) __builtin_amdgcn_exp2f(x)
#define QSCALE 0.18033688011112042f /* 0.125 * log2(e): exp(S) == exp2(S') */
#else
#define EXPW(x) __expf(x)
#define QSCALE 0.125f
#endif

__device__ __forceinline__ float bf2f(unsigned short u) {
    return __uint_as_float(((unsigned int)u) << 16);
}
__device__ __forceinline__ unsigned short f2bf(float f) {
    unsigned int x = __float_as_uint(f);
    x += 0x7fffu + ((x >> 16) & 1u); // RNE
    return (unsigned short)(x >> 16);
}
// Async global->LDS DMA: 16B/lane, lane i lands at lptr + i*16. lptr wave-uniform.
__device__ __forceinline__ void dma16(const void* g, void* l) {
    __builtin_amdgcn_global_load_lds(
        (const __attribute__((address_space(1))) void*)g,
        (__attribute__((address_space(3))) void*)l, 16, 0, 0);
}

// ---- Prepass (2048 blocks x 256):
//  [0,1024)    q*QSCALE -> swizzled bf16 (chunk j at j^(m&7) within 128B row)
//  [1024,1536) k (64i x 2048n) -> kT[b][n][i] bf16, chunk-swizzled (^(n&7))
//  [1536,2048) v (2048n x 64j) -> vS[b][nb][j][nn] bf16, chunk at qc^(j&3)^((j>>2)&3)
__global__ __launch_bounds__(256) void prepass_kernel(
    const float* __restrict__ q, const float* __restrict__ k, const float* __restrict__ v,
    unsigned short* __restrict__ qb,
    unsigned short* __restrict__ kT, unsigned short* __restrict__ vS)
{
    __shared__ unsigned short T[64][68];
    const int bx = blockIdx.x;
    const int t = threadIdx.x;

    if (bx < 1024) {
        int i = bx * 256 + t; // one 16B out-chunk (8 bf16) per thread
        const float4v* src = (const float4v*)q + (size_t)i * 2;
        float4v x0 = src[0], x1 = src[1];
        unsigned int u0 = f2bf(x0[0] * QSCALE) | ((unsigned)f2bf(x0[1] * QSCALE) << 16);
        unsigned int u1 = f2bf(x0[2] * QSCALE) | ((unsigned)f2bf(x0[3] * QSCALE) << 16);
        unsigned int u2 = f2bf(x1[0] * QSCALE) | ((unsigned)f2bf(x1[1] * QSCALE) << 16);
        unsigned int u3 = f2bf(x1[2] * QSCALE) | ((unsigned)f2bf(x1[3] * QSCALE) << 16);
        int b = i >> 14, r = i & 16383, m = r >> 3, j = r & 7;
        *(uint4*)(qb + (size_t)b * BSTRIDE + m * 64 + (j ^ (m & 7)) * 8) =
            make_uint4(u0, u1, u2, u3);
    } else if (bx < 1536) { // k-transpose: tile = all 64 i x 64 n
        int idx = bx - 1024, b = idx >> 5, n0 = (idx & 31) * 64;
        const float* src = k + (size_t)b * BSTRIDE + (size_t)(t >> 2) * 2048 + n0 + (t & 3) * 16;
#pragma unroll
        for (int kk = 0; kk < 4; kk++) {
            float4v x = *(const float4v*)(src + kk * 4);
#pragma unroll
            for (int e = 0; e < 4; e++)
                T[t >> 2][(t & 3) * 16 + kk * 4 + e] = f2bf(x[e]);
        }
        __syncthreads();
        unsigned short* dst = kT + (size_t)b * BSTRIDE;
        int n = t & 63;
#pragma unroll
        for (int jj = 0; jj < 2; jj++) {
            int j = (t >> 6) * 2 + jj;
            ushort4 g0, g1;
#pragma unroll
            for (int e = 0; e < 4; e++) { g0[e] = T[j * 8 + e][n]; g1[e] = T[j * 8 + 4 + e][n]; }
            *(uint4*)(dst + (size_t)(n0 + n) * 64 + (j ^ (n & 7)) * 8) =
                make_uint4(g0.x | ((unsigned)g0.y << 16), g0.z | ((unsigned)g0.w << 16),
                           g1.x | ((unsigned)g1.y << 16), g1.z | ((unsigned)g1.w << 16));
        }
    } else { // v-transpose: tile = 64 n x 64 j
        int idx = bx - 1536, b = idx >> 5, n0 = (idx & 31) * 64;
        const float* src = v + (size_t)b * BSTRIDE + (size_t)n0 * 64 +
                           (size_t)(t >> 2) * 64 + (t & 3) * 16;
#pragma unroll
        for (int kk = 0; kk < 4; kk++) {
            float4v x = *(const float4v*)(src + kk * 4);
#pragma unroll
            for (int e = 0; e < 4; e++)
                T[t >> 2][(t & 3) * 16 + kk * 4 + e] = f2bf(x[e]); // T[n][j]
        }
        __syncthreads();
        unsigned short* dst = vS + (size_t)b * BSTRIDE;
        int j = t & 63, qc = t >> 6;
        int sw = qc ^ (j & 3) ^ ((j >> 2) & 3);
#pragma unroll
        for (int nb = 0; nb < 2; nb++) {
            ushort4 g0, g1;
#pragma unroll
            for (int e = 0; e < 4; e++) {
                g0[e] = T[nb * 32 + qc * 8 + e][j];
                g1[e] = T[nb * 32 + qc * 8 + 4 + e][j];
            }
            *(uint4*)(dst + (size_t)(n0 / 32 + nb) * 2048 + j * 32 + sw * 8) =
                make_uint4(g0.x | ((unsigned)g0.y << 16), g0.z | ((unsigned)g0.w << 16),
                           g1.x | ((unsigned)g1.y << 16), g1.z | ((unsigned)g1.w << 16));
        }
    }
}

// ---- dinv: Dt pair-tiles. Tile (tm=m/16, tp=n/32) is 1024B; lane slot c*64+q*16 holds
// uint4 = 4 bf16-1/D for n-subtile tn=2tp (low 8B) and 2tp+1 (high 8B).
// Grid 512 = 16 mtB(128m) x 32 ng(64n); block 256 = 4 waves, each wave 32m (ms=2).
// Single-barrier double-buffered pipeline over the 16 batches.
__global__ __launch_bounds__(256, 3) void dinv_kernel(
    const unsigned short* __restrict__ qb, const unsigned short* __restrict__ kT,
    unsigned short* __restrict__ Dt)
{
    __shared__ __align__(16) unsigned char smem[49152]; // Sq[2]@0 (16KB ea), Sk[2]@32768 (8KB ea)

    const int tid = threadIdx.x, w = tid >> 6, lane = tid & 63;
    const int c = lane & 15, q = lane >> 4;
    const int mtB = blockIdx.x & 15, ng = blockIdx.x >> 4;
    const int m0 = mtB * 128, n0 = ng * 64;

    float4v Dacc[2][4];
#pragma unroll
    for (int ms = 0; ms < 2; ms++)
#pragma unroll
        for (int nt = 0; nt < 4; nt++) Dacc[ms][nt] = (float4v){0.f, 0.f, 0.f, 0.f};

    { // stage batch 0 (wave w: Q chunks w*4..+3, K chunks w*2..+1)
        const char* qg = (const char*)(qb + (size_t)m0 * 64);
        const char* kg = (const char*)(kT + (size_t)n0 * 64);
#pragma unroll
        for (int kk = 0; kk < 4; kk++)
            dma16(qg + (w * 4 + kk) * 1024 + lane * 16, (char*)smem + (w * 4 + kk) * 1024);
        dma16(kg + (w * 2 + 0) * 1024 + lane * 16, (char*)smem + 32768 + (w * 2 + 0) * 1024);
        dma16(kg + (w * 2 + 1) * 1024 + lane * 16, (char*)smem + 32768 + (w * 2 + 1) * 1024);
    }

    for (int bb = 0; bb < BATCH; bb++) {
        const int p = bb & 1;
        asm volatile("s_waitcnt vmcnt(0)" ::: "memory");
        asm volatile("s_barrier" ::: "memory"); // buf p landed; buf p^1 reads done
        if (bb < BATCH - 1) {
            const char* qg = (const char*)(qb + (size_t)(bb + 1) * BSTRIDE + (size_t)m0 * 64);
            const char* kg = (const char*)(kT + (size_t)(bb + 1) * BSTRIDE + (size_t)n0 * 64);
#pragma unroll
            for (int kk = 0; kk < 4; kk++)
                dma16(qg + (w * 4 + kk) * 1024 + lane * 16,
                      (char*)smem + (p ^ 1) * 16384 + (w * 4 + kk) * 1024);
            dma16(kg + (w * 2 + 0) * 1024 + lane * 16,
                  (char*)smem + 32768 + (p ^ 1) * 8192 + (w * 2 + 0) * 1024);
            dma16(kg + (w * 2 + 1) * 1024 + lane * 16,
                  (char*)smem + 32768 + (p ^ 1) * 8192 + (w * 2 + 1) * 1024);
        }
        const char* sq = (const char*)smem + p * 16384;
        const char* sk = (const char*)smem + 32768 + p * 8192;
        short8 Qf[2][2];
#pragma unroll
        for (int ms = 0; ms < 2; ms++)
#pragma unroll
            for (int h = 0; h < 2; h++)
                Qf[ms][h] = *(const short8*)(sq + (w * 32 + ms * 16 + c) * 128 +
                                             ((h * 4 + q) ^ (c & 7)) * 16);
#pragma unroll
        for (int nt = 0; nt < 4; nt++) {
            short8 A0 = *(const short8*)(sk + (nt * 16 + c) * 128 + ((q) ^ (c & 7)) * 16);
            short8 A1 = *(const short8*)(sk + (nt * 16 + c) * 128 + ((4 + q) ^ (c & 7)) * 16);
#pragma unroll
            for (int ms = 0; ms < 2; ms++) {
                float4v d = (float4v){0.f, 0.f, 0.f, 0.f};
                d = __builtin_amdgcn_mfma_f32_16x16x32_bf16(A0, Qf[ms][0], d, 0, 0, 0);
                d = __builtin_amdgcn_mfma_f32_16x16x32_bf16(A1, Qf[ms][1], d, 0, 0, 0);
#pragma unroll
                for (int r = 0; r < 4; r++) Dacc[ms][nt][r] += EXPW(d[r]);
            }
        }
    }

#pragma unroll
    for (int ms = 0; ms < 2; ms++)
#pragma unroll
        for (int nt = 0; nt < 4; nt++) {
            unsigned int x = f2bf(__builtin_amdgcn_rcpf(Dacc[ms][nt][0])) |
                             ((unsigned)f2bf(__builtin_amdgcn_rcpf(Dacc[ms][nt][1])) << 16);
            unsigned int y = f2bf(__builtin_amdgcn_rcpf(Dacc[ms][nt][2])) |
                             ((unsigned)f2bf(__builtin_amdgcn_rcpf(Dacc[ms][nt][3])) << 16);
            size_t tm = (size_t)(mtB * 8 + w * 2 + ms);
            size_t tp = (size_t)(ng * 2 + (nt >> 1));
            *(uint2*)((char*)Dt + (tm * 64 + tp) * 1024 + c * 64 + q * 16 + (nt & 1) * 8) =
                make_uint2(x, y);
        }
}

// ---- Main: out_b = (exp(S_b)*Dinv) @ V_b. Grid 512 = 16b x 32mt(64m); 2 blocks/CU.
// Block 512 = 8 waves: g = w>>2 (32m sub, ms=2), ns = w&3 (512n split, 16 steps of 32).
// One s_barrier/step, K-frags reused across ms (0.75 KB LDS/MFMA), Dt uint4 prefetch,
// shfl C->A transform. Epilogue: 2-round LDS reduction (pitch 68), float4 stores.
__global__ __launch_bounds__(512, 4) void attn_main_kernel(
    const unsigned short* __restrict__ qb, const unsigned short* __restrict__ kT,
    const unsigned short* __restrict__ vS, const unsigned short* __restrict__ Dt,
    float* __restrict__ out)
{
    __shared__ __align__(16) unsigned char smem[65536];
    // staging: Sk[ns][p] @ ns*8192+p*4096 ; Sv[ns][p] @ 32768+ns*8192+p*4096
    // epilogue: two fp32 copies (64 x pitch68) @ 0 and 17408

    const int tid = threadIdx.x, w = tid >> 6, lane = tid & 63;
    const int c = lane & 15, q = lane >> 4;
    const int g = w >> 2, ns = w & 3;
    const int b = blockIdx.x & 15, mt = blockIdx.x >> 4; // mt 0..31
    const int m0 = mt * 64;
    const int nbase = ns * 512;

    const unsigned short* qb_b = qb + (size_t)b * BSTRIDE;
    const char* kbase = (const char*)(kT + (size_t)b * BSTRIDE);
    const char* vbase = (const char*)(vS + (size_t)b * BSTRIDE);
    char* skb = (char*)smem + ns * 8192;
    char* svb = (char*)smem + 32768 + ns * 8192;

    short8 Qf[2][2];
#pragma unroll
    for (int ms = 0; ms < 2; ms++)
#pragma unroll
        for (int h = 0; h < 2; h++)
            Qf[ms][h] = *(const short8*)(qb_b + (m0 + g * 32 + ms * 16 + c) * 64 +
                                         ((h * 4 + q) ^ (c & 7)) * 8);
    float4v acc[2][4];
#pragma unroll
    for (int ms = 0; ms < 2; ms++)
#pragma unroll
        for (int jt = 0; jt < 4; jt++) acc[ms][jt] = (float4v){0.f, 0.f, 0.f, 0.f};

    // Dt bases: tile-pair row for tm = mt*4 + g*2 + ms, starting tp = ns*16
    const char* dtw0 = (const char*)Dt +
        ((size_t)(mt * 4 + g * 2 + 0) * 64 + ns * 16) * 1024 + c * 64 + q * 16;
    const char* dtw1 = dtw0 + (size_t)64 * 1024;

    // stage step 0: wave (g,ns): K chunks 2g,2g+1 and V chunks 2g,2g+1 of its ns tile
    dma16(kbase + (size_t)nbase * 128 + (2 * g + 0) * 1024 + lane * 16, skb + (2 * g + 0) * 1024);
    dma16(kbase + (size_t)nbase * 128 + (2 * g + 1) * 1024 + lane * 16, skb + (2 * g + 1) * 1024);
    dma16(vbase + (size_t)(ns * 16) * 4096 + (2 * g + 0) * 1024 + lane * 16, svb + (2 * g + 0) * 1024);
    dma16(vbase + (size_t)(ns * 16) * 4096 + (2 * g + 1) * 1024 + lane * 16, svb + (2 * g + 1) * 1024);
    uint4 du[2];
    du[0] = *(const uint4*)(dtw0);
    du[1] = *(const uint4*)(dtw1);

    for (int st = 0; st < 16; st++) {
        const int p = st & 1;
        asm volatile("s_waitcnt vmcnt(0)" ::: "memory");
        asm volatile("s_barrier" ::: "memory"); // buf p landed; buf p^1 reads done

        uint4 nu[2] = {du[0], du[1]};
        if (st < 15) { // prefetch next step (safe after barrier)
            const int n1 = nbase + (st + 1) * 32;
            dma16(kbase + (size_t)n1 * 128 + (2 * g + 0) * 1024 + lane * 16,
                  skb + (p ^ 1) * 4096 + (2 * g + 0) * 1024);
            dma16(kbase + (size_t)n1 * 128 + (2 * g + 1) * 1024 + lane * 16,
                  skb + (p ^ 1) * 4096 + (2 * g + 1) * 1024);
            dma16(vbase + (size_t)(ns * 16 + st + 1) * 4096 + (2 * g + 0) * 1024 + lane * 16,
                  svb + (p ^ 1) * 4096 + (2 * g + 0) * 1024);
            dma16(vbase + (size_t)(ns * 16 + st + 1) * 4096 + (2 * g + 1) * 1024 + lane * 16,
                  svb + (p ^ 1) * 4096 + (2 * g + 1) * 1024);
            nu[0] = *(const uint4*)(dtw0 + (size_t)(st + 1) * 1024);
            nu[1] = *(const uint4*)(dtw1 + (size_t)(st + 1) * 1024);
        }

        // GEMM1 (S^T) + exp2*Dinv -> packed bf16 pairs; K frags shared across ms
        const char* skp = skb + p * 4096;
        unsigned int pr[2][2][2]; // [ms][nt][pair]
#pragma unroll
        for (int nt = 0; nt < 2; nt++) {
            short8 A0 = *(const short8*)(skp + (nt * 16 + c) * 128 + ((q) ^ (c & 7)) * 16);
            short8 A1 = *(const short8*)(skp + (nt * 16 + c) * 128 + ((4 + q) ^ (c & 7)) * 16);
#pragma unroll
            for (int ms = 0; ms < 2; ms++) {
                float4v d = (float4v){0.f, 0.f, 0.f, 0.f};
                d = __builtin_amdgcn_mfma_f32_16x16x32_bf16(A0, Qf[ms][0], d, 0, 0, 0);
                d = __builtin_amdgcn_mfma_f32_16x16x32_bf16(A1, Qf[ms][1], d, 0, 0, 0);
                unsigned int ux = nt ? du[ms].z : du[ms].x;
                unsigned int uy = nt ? du[ms].w : du[ms].y;
                float p0 = EXPW(d[0]) * __uint_as_float(ux << 16);
                float p1 = EXPW(d[1]) * __uint_as_float(ux & 0xffff0000u);
                float p2 = EXPW(d[2]) * __uint_as_float(uy << 16);
                float p3 = EXPW(d[3]) * __uint_as_float(uy & 0xffff0000u);
                pr[ms][nt][0] = f2bf(p0) | ((unsigned)f2bf(p1) << 16);
                pr[ms][nt][1] = f2bf(p2) | ((unsigned)f2bf(p3) << 16);
            }
        }

        // C-frag -> A-frag transform via shfl (verified R8 mapping), per ms
        union PU { unsigned int i[4]; short8 s; };
        PU pu0, pu1;
#pragma unroll
        for (int t = 0; t < 4; t++) {
            int src = (2 * (q & 1) + (t >> 1)) * 16 + c;
            int a0 = __shfl((int)pr[0][0][t & 1], src);
            int b0 = __shfl((int)pr[0][1][t & 1], src);
            pu0.i[t] = (unsigned int)((q >= 2) ? b0 : a0);
            int a1 = __shfl((int)pr[1][0][t & 1], src);
            int b1 = __shfl((int)pr[1][1][t & 1], src);
            pu1.i[t] = (unsigned int)((q >= 2) ? b1 : a1);
        }

        // GEMM2: acc += P @ V; V frags shared across ms
        const char* svp = svb + p * 4096;
#pragma unroll
        for (int jt = 0; jt < 4; jt++) {
            short8 Vf = *(const short8*)(svp + (jt * 16 + c) * 64 +
                                         ((q ^ (c & 3) ^ ((c >> 2) & 3))) * 16);
            acc[0][jt] = __builtin_amdgcn_mfma_f32_16x16x32_bf16(pu0.s, Vf, acc[0][jt], 0, 0, 0);
            acc[1][jt] = __builtin_amdgcn_mfma_f32_16x16x32_bf16(pu1.s, Vf, acc[1][jt], 0, 0, 0);
        }
        du[0] = nu[0]; du[1] = nu[1];
    }

    // ---- Epilogue: 2-round ns-reduction in LDS (pitch 68 = conflict-free), then store ----
    __syncthreads(); // all staging reads done; safe to overwrite smem
    {
        float* cpy = (float*)((char*)smem + (ns & 1) * 17408);
        if (ns < 2) {
#pragma unroll
            for (int ms = 0; ms < 2; ms++)
#pragma unroll
                for (int jt = 0; jt < 4; jt++)
#pragma unroll
                    for (int r = 0; r < 4; r++)
                        cpy[(g * 32 + ms * 16 + q * 4 + r) * 68 + jt * 16 + c] = acc[ms][jt][r];
        }
    }
    __syncthreads();
    {
        float* cpy = (float*)((char*)smem + (ns & 1) * 17408);
        if (ns >= 2) {
#pragma unroll
            for (int ms = 0; ms < 2; ms++)
#pragma unroll
                for (int jt = 0; jt < 4; jt++)
#pragma unroll
                    for (int r = 0; r < 4; r++)
                        cpy[(g * 32 + ms * 16 + q * 4 + r) * 68 + jt * 16 + c] += acc[ms][jt][r];
        }
    }
    __syncthreads();
    {
        int ml = tid >> 3, j0 = (tid & 7) * 8;
        const float* c0 = (const float*)smem + ml * 68 + j0;
        const float* c1 = (const float*)((char*)smem + 17408) + ml * 68 + j0;
        float4v s0 = *(const float4v*)c0 + *(const float4v*)c1;
        float4v s1 = *(const float4v*)(c0 + 4) + *(const float4v*)(c1 + 4);
        float* dst = out + ((size_t)b * CDIM + m0 + ml) * LDIM + j0;
        *(float4v*)dst = s0;
        *(float4v*)(dst + 4) = s1;
    }
}

extern "C" void kernel_launch(void* const* d_in, const int* in_sizes, int n_in,
                              void* d_out, int out_size, void* d_ws, size_t ws_size,
                              hipStream_t stream) {
    const float* q = (const float*)d_in[0];
    const float* k = (const float*)d_in[1];
    const float* v = (const float*)d_in[2];
    float* out = (float*)d_out;

    unsigned short* qb = (unsigned short*)d_ws;        // 4 MB bf16 swizzled (q*QSCALE)
    unsigned short* kT = qb + (size_t)BATCH * BSTRIDE; // 4 MB bf16 swizzled [b][n][i]
    unsigned short* vS = kT + (size_t)BATCH * BSTRIDE; // 4 MB bf16 tiled [b][nb][j][nn]
    unsigned short* Dt = vS + (size_t)BATCH * BSTRIDE; // 8 MB bf16 1/D pair-tiles

    prepass_kernel<<<2048, 256, 0, stream>>>(q, k, v, qb, kT, vS);
    dinv_kernel<<<512, 256, 0, stream>>>(qb, kT, Dt);
    attn_main_kernel<<<512, 512, 0, stream>>>(qb, kT, vS, Dt, out);
}

// Round 10
// 124.069 us; speedup vs baseline: 1.0205x; 1.0205x over previous
//
#include <hip/hip_runtime.h>

typedef __attribute__((ext_vector_type(8))) short short8;
typedef __attribute__((ext_vector_type(4))) float float4v;

#define BATCH 16
#define CDIM 2048
#define LDIM 64
#define BSTRIDE (CDIM * LDIM) /* 131072 elems per batch */

#if __has_builtin(__builtin_amdgcn_exp2f)
#define EXPW(x) __builtin_amdgcn_exp2f(x)
#define QSCALE 0.18033688011112042f /* 0.125 * log2(e): exp(S) == exp2(S') */
#else
#define EXPW(x) __expf(x)
#define QSCALE 0.125f
#endif

__device__ __forceinline__ float bf2f(unsigned short u) {
    return __uint_as_float(((unsigned int)u) << 16);
}
__device__ __forceinline__ unsigned short f2bf(float f) {
    unsigned int x = __float_as_uint(f);
    x += 0x7fffu + ((x >> 16) & 1u); // RNE
    return (unsigned short)(x >> 16);
}
// Pack two f32 -> two bf16 (low = a, high = b), RNE. One v_cvt_pk_bf16_f32 if available.
#if __has_builtin(__builtin_amdgcn_cvt_pk_bf16_f32)
__device__ __forceinline__ unsigned int pk2bf(float a, float b) {
    auto t = __builtin_amdgcn_cvt_pk_bf16_f32(a, b);
    unsigned int u;
    __builtin_memcpy(&u, &t, 4);
    return u;
}
#else
__device__ __forceinline__ unsigned int pk2bf(float a, float b) {
    return f2bf(a) | ((unsigned)f2bf(b) << 16);
}
#endif
// Async global->LDS DMA: 16B/lane, lane i lands at lptr + i*16. lptr wave-uniform.
__device__ __forceinline__ void dma16(const void* g, void* l) {
    __builtin_amdgcn_global_load_lds(
        (const __attribute__((address_space(1))) void*)g,
        (__attribute__((address_space(3))) void*)l, 16, 0, 0);
}

// ---- Prepass (1536 blocks x 256):
//  [0,1024)    q*QSCALE -> swizzled bf16 (chunk j at j^(m&7) within 128B row)
//  [1024,1536) k (64i x 2048n) -> kT[b][n][i] bf16, chunk-swizzled (^(n&7))
__global__ __launch_bounds__(256) void prepass_kernel(
    const float* __restrict__ q, const float* __restrict__ k,
    unsigned short* __restrict__ qb, unsigned short* __restrict__ kT)
{
    __shared__ float T[64][68];
    const int bx = blockIdx.x;
    const int t = threadIdx.x;

    if (bx < 1024) {
        int i = bx * 256 + t; // one 16B out-chunk (8 bf16) per thread
        const float4v* src = (const float4v*)q + (size_t)i * 2;
        float4v x0 = src[0], x1 = src[1];
        unsigned int u0 = pk2bf(x0[0] * QSCALE, x0[1] * QSCALE);
        unsigned int u1 = pk2bf(x0[2] * QSCALE, x0[3] * QSCALE);
        unsigned int u2 = pk2bf(x1[0] * QSCALE, x1[1] * QSCALE);
        unsigned int u3 = pk2bf(x1[2] * QSCALE, x1[3] * QSCALE);
        int b = i >> 14, r = i & 16383, m = r >> 3, j = r & 7;
        *(uint4*)(qb + (size_t)b * BSTRIDE + m * 64 + (j ^ (m & 7)) * 8) =
            make_uint4(u0, u1, u2, u3);
    } else { // k-transpose: tile = all 64 i x 64 n
        int idx = bx - 1024, b = idx >> 5, n0 = (idx & 31) * 64;
        const float* src = k + (size_t)b * BSTRIDE + (size_t)(t >> 2) * 2048 + n0 + (t & 3) * 16;
#pragma unroll
        for (int kk = 0; kk < 4; kk++) {
            float4v x = *(const float4v*)(src + kk * 4);
#pragma unroll
            for (int e = 0; e < 4; e++)
                T[t >> 2][(t & 3) * 16 + kk * 4 + e] = x[e];
        }
        __syncthreads();
        unsigned short* dst = kT + (size_t)b * BSTRIDE;
        int n = t & 63;
#pragma unroll
        for (int jj = 0; jj < 2; jj++) {
            int j = (t >> 6) * 2 + jj;
            *(uint4*)(dst + (size_t)(n0 + n) * 64 + (j ^ (n & 7)) * 8) =
                make_uint4(pk2bf(T[j * 8 + 0][n], T[j * 8 + 1][n]),
                           pk2bf(T[j * 8 + 2][n], T[j * 8 + 3][n]),
                           pk2bf(T[j * 8 + 4][n], T[j * 8 + 5][n]),
                           pk2bf(T[j * 8 + 6][n], T[j * 8 + 7][n]));
        }
    }
}

// ---- dinv (+ fused v-transpose): blocks [0,512) compute Dt; [512,1024) transpose V.
// dinv: Dt pair-tiles. Tile (tm=m/16, tp=n/32) is 1024B; lane slot c*64+q*16 holds
// uint4 = 4 bf16-1/D for n-subtile 2tp (low 8B) and 2tp+1 (high 8B).
// dinv grid 512 = 16 mtB(128m) x 32 ng(64n); 4 waves/block, wave=32m (ms=2);
// single-barrier double-buffered pipeline over the 16 batches (VALU/exp-bound, so the
// co-scheduled v-transpose blocks ride the idle memory pipes).
__global__ __launch_bounds__(256, 3) void dinv_vpre_kernel(
    const unsigned short* __restrict__ qb, const unsigned short* __restrict__ kT,
    const float* __restrict__ v, unsigned short* __restrict__ vS,
    unsigned short* __restrict__ Dt)
{
    __shared__ __align__(16) unsigned char smem[49152]; // dinv: Sq[2]@0, Sk[2]@32768 ; vpre: float T[64][68]

    const int tid = threadIdx.x;

    if (blockIdx.x >= 512) { // ---- v-transpose: tile = 64 n x 64 j ----
        float (*T)[68] = (float(*)[68])smem;
        int idx = blockIdx.x - 512, b = idx >> 5, n0 = (idx & 31) * 64;
        const float* src = v + (size_t)b * BSTRIDE + (size_t)n0 * 64 +
                           (size_t)(tid >> 2) * 64 + (tid & 3) * 16;
#pragma unroll
        for (int kk = 0; kk < 4; kk++) {
            float4v x = *(const float4v*)(src + kk * 4);
#pragma unroll
            for (int e = 0; e < 4; e++)
                T[tid >> 2][(tid & 3) * 16 + kk * 4 + e] = x[e]; // T[n][j]
        }
        __syncthreads();
        unsigned short* dst = vS + (size_t)b * BSTRIDE;
        int j = tid & 63, qc = tid >> 6;
        int sw = qc ^ (j & 3) ^ ((j >> 2) & 3);
#pragma unroll
        for (int nb = 0; nb < 2; nb++) {
            *(uint4*)(dst + (size_t)(n0 / 32 + nb) * 2048 + j * 32 + sw * 8) =
                make_uint4(pk2bf(T[nb * 32 + qc * 8 + 0][j], T[nb * 32 + qc * 8 + 1][j]),
                           pk2bf(T[nb * 32 + qc * 8 + 2][j], T[nb * 32 + qc * 8 + 3][j]),
                           pk2bf(T[nb * 32 + qc * 8 + 4][j], T[nb * 32 + qc * 8 + 5][j]),
                           pk2bf(T[nb * 32 + qc * 8 + 6][j], T[nb * 32 + qc * 8 + 7][j]));
        }
        return;
    }

    // ---- dinv ----
    const int w = tid >> 6, lane = tid & 63;
    const int c = lane & 15, q = lane >> 4;
    const int mtB = blockIdx.x & 15, ng = blockIdx.x >> 4;
    const int m0 = mtB * 128, n0 = ng * 64;

    float4v Dacc[2][4];
#pragma unroll
    for (int ms = 0; ms < 2; ms++)
#pragma unroll
        for (int nt = 0; nt < 4; nt++) Dacc[ms][nt] = (float4v){0.f, 0.f, 0.f, 0.f};

    { // stage batch 0 (wave w: Q chunks w*4..+3, K chunks w*2..+1)
        const char* qg = (const char*)(qb + (size_t)m0 * 64);
        const char* kg = (const char*)(kT + (size_t)n0 * 64);
#pragma unroll
        for (int kk = 0; kk < 4; kk++)
            dma16(qg + (w * 4 + kk) * 1024 + lane * 16, (char*)smem + (w * 4 + kk) * 1024);
        dma16(kg + (w * 2 + 0) * 1024 + lane * 16, (char*)smem + 32768 + (w * 2 + 0) * 1024);
        dma16(kg + (w * 2 + 1) * 1024 + lane * 16, (char*)smem + 32768 + (w * 2 + 1) * 1024);
    }

    for (int bb = 0; bb < BATCH; bb++) {
        const int p = bb & 1;
        asm volatile("s_waitcnt vmcnt(0)" ::: "memory");
        asm volatile("s_barrier" ::: "memory"); // buf p landed; buf p^1 reads done
        if (bb < BATCH - 1) {
            const char* qg = (const char*)(qb + (size_t)(bb + 1) * BSTRIDE + (size_t)m0 * 64);
            const char* kg = (const char*)(kT + (size_t)(bb + 1) * BSTRIDE + (size_t)n0 * 64);
#pragma unroll
            for (int kk = 0; kk < 4; kk++)
                dma16(qg + (w * 4 + kk) * 1024 + lane * 16,
                      (char*)smem + (p ^ 1) * 16384 + (w * 4 + kk) * 1024);
            dma16(kg + (w * 2 + 0) * 1024 + lane * 16,
                  (char*)smem + 32768 + (p ^ 1) * 8192 + (w * 2 + 0) * 1024);
            dma16(kg + (w * 2 + 1) * 1024 + lane * 16,
                  (char*)smem + 32768 + (p ^ 1) * 8192 + (w * 2 + 1) * 1024);
        }
        const char* sq = (const char*)smem + p * 16384;
        const char* sk = (const char*)smem + 32768 + p * 8192;
        short8 Qf[2][2];
#pragma unroll
        for (int ms = 0; ms < 2; ms++)
#pragma unroll
            for (int h = 0; h < 2; h++)
                Qf[ms][h] = *(const short8*)(sq + (w * 32 + ms * 16 + c) * 128 +
                                             ((h * 4 + q) ^ (c & 7)) * 16);
#pragma unroll
        for (int nt = 0; nt < 4; nt++) {
            short8 A0 = *(const short8*)(sk + (nt * 16 + c) * 128 + ((q) ^ (c & 7)) * 16);
            short8 A1 = *(const short8*)(sk + (nt * 16 + c) * 128 + ((4 + q) ^ (c & 7)) * 16);
#pragma unroll
            for (int ms = 0; ms < 2; ms++) {
                float4v d = (float4v){0.f, 0.f, 0.f, 0.f};
                d = __builtin_amdgcn_mfma_f32_16x16x32_bf16(A0, Qf[ms][0], d, 0, 0, 0);
                d = __builtin_amdgcn_mfma_f32_16x16x32_bf16(A1, Qf[ms][1], d, 0, 0, 0);
#pragma unroll
                for (int r = 0; r < 4; r++) Dacc[ms][nt][r] += EXPW(d[r]);
            }
        }
    }

#pragma unroll
    for (int ms = 0; ms < 2; ms++)
#pragma unroll
        for (int nt = 0; nt < 4; nt++) {
            unsigned int x = pk2bf(__builtin_amdgcn_rcpf(Dacc[ms][nt][0]),
                                   __builtin_amdgcn_rcpf(Dacc[ms][nt][1]));
            unsigned int y = pk2bf(__builtin_amdgcn_rcpf(Dacc[ms][nt][2]),
                                   __builtin_amdgcn_rcpf(Dacc[ms][nt][3]));
            size_t tm = (size_t)(mtB * 8 + w * 2 + ms);
            size_t tp = (size_t)(ng * 2 + (nt >> 1));
            *(uint2*)((char*)Dt + (tm * 64 + tp) * 1024 + c * 64 + q * 16 + (nt & 1) * 8) =
                make_uint2(x, y);
        }
}

// ---- Main: out_b = (exp(S_b)*Dinv) @ V_b. Grid 512 = 16b x 32mt(64m); 2 blocks/CU.
// Block 512 = 8 waves: g = w>>2 (32m sub, ms=2), ns = w&3 (512n split, 16 steps of 32).
// One s_barrier/step, K/V-frags reused across ms, Dt uint4 prefetch, shfl C->A transform.
// Epilogue: 2-round LDS reduction (pitch 68), float4 stores.
__global__ __launch_bounds__(512, 4) void attn_main_kernel(
    const unsigned short* __restrict__ qb, const unsigned short* __restrict__ kT,
    const unsigned short* __restrict__ vS, const unsigned short* __restrict__ Dt,
    float* __restrict__ out)
{
    __shared__ __align__(16) unsigned char smem[65536];
    // staging: Sk[ns][p] @ ns*8192+p*4096 ; Sv[ns][p] @ 32768+ns*8192+p*4096
    // epilogue: two fp32 copies (64 x pitch68) @ 0 and 17408

    const int tid = threadIdx.x, w = tid >> 6, lane = tid & 63;
    const int c = lane & 15, q = lane >> 4;
    const int g = w >> 2, ns = w & 3;
    const int b = blockIdx.x & 15, mt = blockIdx.x >> 4; // mt 0..31
    const int m0 = mt * 64;
    const int nbase = ns * 512;

    const unsigned short* qb_b = qb + (size_t)b * BSTRIDE;
    const char* kbase = (const char*)(kT + (size_t)b * BSTRIDE);
    const char* vbase = (const char*)(vS + (size_t)b * BSTRIDE);
    char* skb = (char*)smem + ns * 8192;
    char* svb = (char*)smem + 32768 + ns * 8192;

    short8 Qf[2][2];
#pragma unroll
    for (int ms = 0; ms < 2; ms++)
#pragma unroll
        for (int h = 0; h < 2; h++)
            Qf[ms][h] = *(const short8*)(qb_b + (m0 + g * 32 + ms * 16 + c) * 64 +
                                         ((h * 4 + q) ^ (c & 7)) * 8);
    float4v acc[2][4];
#pragma unroll
    for (int ms = 0; ms < 2; ms++)
#pragma unroll
        for (int jt = 0; jt < 4; jt++) acc[ms][jt] = (float4v){0.f, 0.f, 0.f, 0.f};

    // Dt bases: tile-pair row for tm = mt*4 + g*2 + ms, starting tp = ns*16
    const char* dtw0 = (const char*)Dt +
        ((size_t)(mt * 4 + g * 2 + 0) * 64 + ns * 16) * 1024 + c * 64 + q * 16;
    const char* dtw1 = dtw0 + (size_t)64 * 1024;

    // stage step 0: wave (g,ns): K chunks 2g,2g+1 and V chunks 2g,2g+1 of its ns tile
    dma16(kbase + (size_t)nbase * 128 + (2 * g + 0) * 1024 + lane * 16, skb + (2 * g + 0) * 1024);
    dma16(kbase + (size_t)nbase * 128 + (2 * g + 1) * 1024 + lane * 16, skb + (2 * g + 1) * 1024);
    dma16(vbase + (size_t)(ns * 16) * 4096 + (2 * g + 0) * 1024 + lane * 16, svb + (2 * g + 0) * 1024);
    dma16(vbase + (size_t)(ns * 16) * 4096 + (2 * g + 1) * 1024 + lane * 16, svb + (2 * g + 1) * 1024);
    uint4 du[2];
    du[0] = *(const uint4*)(dtw0);
    du[1] = *(const uint4*)(dtw1);

    for (int st = 0; st < 16; st++) {
        const int p = st & 1;
        asm volatile("s_waitcnt vmcnt(0)" ::: "memory");
        asm volatile("s_barrier" ::: "memory"); // buf p landed; buf p^1 reads done

        uint4 nu[2] = {du[0], du[1]};
        if (st < 15) { // prefetch next step (safe after barrier)
            const int n1 = nbase + (st + 1) * 32;
            dma16(kbase + (size_t)n1 * 128 + (2 * g + 0) * 1024 + lane * 16,
                  skb + (p ^ 1) * 4096 + (2 * g + 0) * 1024);
            dma16(kbase + (size_t)n1 * 128 + (2 * g + 1) * 1024 + lane * 16,
                  skb + (p ^ 1) * 4096 + (2 * g + 1) * 1024);
            dma16(vbase + (size_t)(ns * 16 + st + 1) * 4096 + (2 * g + 0) * 1024 + lane * 16,
                  svb + (p ^ 1) * 4096 + (2 * g + 0) * 1024);
            dma16(vbase + (size_t)(ns * 16 + st + 1) * 4096 + (2 * g + 1) * 1024 + lane * 16,
                  svb + (p ^ 1) * 4096 + (2 * g + 1) * 1024);
            nu[0] = *(const uint4*)(dtw0 + (size_t)(st + 1) * 1024);
            nu[1] = *(const uint4*)(dtw1 + (size_t)(st + 1) * 1024);
        }

        // GEMM1 (S^T) + exp2*Dinv -> packed bf16 pairs; K frags shared across ms
        const char* skp = skb + p * 4096;
        unsigned int pr[2][2][2]; // [ms][nt][pair]
#pragma unroll
        for (int nt = 0; nt < 2; nt++) {
            short8 A0 = *(const short8*)(skp + (nt * 16 + c) * 128 + ((q) ^ (c & 7)) * 16);
            short8 A1 = *(const short8*)(skp + (nt * 16 + c) * 128 + ((4 + q) ^ (c & 7)) * 16);
#pragma unroll
            for (int ms = 0; ms < 2; ms++) {
                float4v d = (float4v){0.f, 0.f, 0.f, 0.f};
                d = __builtin_amdgcn_mfma_f32_16x16x32_bf16(A0, Qf[ms][0], d, 0, 0, 0);
                d = __builtin_amdgcn_mfma_f32_16x16x32_bf16(A1, Qf[ms][1], d, 0, 0, 0);
                unsigned int ux = nt ? du[ms].z : du[ms].x;
                unsigned int uy = nt ? du[ms].w : du[ms].y;
                pr[ms][nt][0] = pk2bf(EXPW(d[0]) * __uint_as_float(ux << 16),
                                      EXPW(d[1]) * __uint_as_float(ux & 0xffff0000u));
                pr[ms][nt][1] = pk2bf(EXPW(d[2]) * __uint_as_float(uy << 16),
                                      EXPW(d[3]) * __uint_as_float(uy & 0xffff0000u));
            }
        }

        // C-frag -> A-frag transform via shfl (verified R8/R9 mapping), per ms
        union PU { unsigned int i[4]; short8 s; };
        PU pu0, pu1;
#pragma unroll
        for (int t = 0; t < 4; t++) {
            int src = (2 * (q & 1) + (t >> 1)) * 16 + c;
            int a0 = __shfl((int)pr[0][0][t & 1], src);
            int b0 = __shfl((int)pr[0][1][t & 1], src);
            pu0.i[t] = (unsigned int)((q >= 2) ? b0 : a0);
            int a1 = __shfl((int)pr[1][0][t & 1], src);
            int b1 = __shfl((int)pr[1][1][t & 1], src);
            pu1.i[t] = (unsigned int)((q >= 2) ? b1 : a1);
        }

        // GEMM2: acc += P @ V; V frags shared across ms
        const char* svp = svb + p * 4096;
#pragma unroll
        for (int jt = 0; jt < 4; jt++) {
            short8 Vf = *(const short8*)(svp + (jt * 16 + c) * 64 +
                                         ((q ^ (c & 3) ^ ((c >> 2) & 3))) * 16);
            acc[0][jt] = __builtin_amdgcn_mfma_f32_16x16x32_bf16(pu0.s, Vf, acc[0][jt], 0, 0, 0);
            acc[1][jt] = __builtin_amdgcn_mfma_f32_16x16x32_bf16(pu1.s, Vf, acc[1][jt], 0, 0, 0);
        }
        du[0] = nu[0]; du[1] = nu[1];
    }

    // ---- Epilogue: 2-round ns-reduction in LDS (pitch 68 = conflict-free), then store ----
    __syncthreads(); // all staging reads done; safe to overwrite smem
    {
        float* cpy = (float*)((char*)smem + (ns & 1) * 17408);
        if (ns < 2) {
#pragma unroll
            for (int ms = 0; ms < 2; ms++)
#pragma unroll
                for (int jt = 0; jt < 4; jt++)
#pragma unroll
                    for (int r = 0; r < 4; r++)
                        cpy[(g * 32 + ms * 16 + q * 4 + r) * 68 + jt * 16 + c] = acc[ms][jt][r];
        }
    }
    __syncthreads();
    {
        float* cpy = (float*)((char*)smem + (ns & 1) * 17408);
        if (ns >= 2) {
#pragma unroll
            for (int ms = 0; ms < 2; ms++)
#pragma unroll
                for (int jt = 0; jt < 4; jt++)
#pragma unroll
                    for (int r = 0; r < 4; r++)
                        cpy[(g * 32 + ms * 16 + q * 4 + r) * 68 + jt * 16 + c] += acc[ms][jt][r];
        }
    }
    __syncthreads();
    {
        int ml = tid >> 3, j0 = (tid & 7) * 8;
        const float* c0 = (const float*)smem + ml * 68 + j0;
        const float* c1 = (const float*)((char*)smem + 17408) + ml * 68 + j0;
        float4v s0 = *(const float4v*)c0 + *(const float4v*)c1;
        float4v s1 = *(const float4v*)(c0 + 4) + *(const float4v*)(c1 + 4);
        float* dst = out + ((size_t)b * CDIM + m0 + ml) * LDIM + j0;
        *(float4v*)dst = s0;
        *(float4v*)(dst + 4) = s1;
    }
}

extern "C" void kernel_launch(void* const* d_in, const int* in_sizes, int n_in,
                              void* d_out, int out_size, void* d_ws, size_t ws_size,
                              hipStream_t stream) {
    const float* q = (const float*)d_in[0];
    const float* k = (const float*)d_in[1];
    const float* v = (const float*)d_in[2];
    float* out = (float*)d_out;

    unsigned short* qb = (unsigned short*)d_ws;        // 4 MB bf16 swizzled (q*QSCALE)
    unsigned short* kT = qb + (size_t)BATCH * BSTRIDE; // 4 MB bf16 swizzled [b][n][i]
    unsigned short* vS = kT + (size_t)BATCH * BSTRIDE; // 4 MB bf16 tiled [b][nb][j][nn]
    unsigned short* Dt = vS + (size_t)BATCH * BSTRIDE; // 8 MB bf16 1/D pair-tiles

    prepass_kernel<<<1536, 256, 0, stream>>>(q, k, qb, kT);
    dinv_vpre_kernel<<<1024, 256, 0, stream>>>(qb, kT, v, vS, Dt);
    attn_main_kernel<<<512, 512, 0, stream>>>(qb, kT, vS, Dt, out);
}